// Round 2
// baseline (132.179 us; speedup 1.0000x reference)
//
#include <hip/hip_runtime.h>

// ---------------------------------------------------------------------------
// Temporal MHA (MI355X/gfx950), B=256, S=176 (8t x 22j), D_in=128, H=8, Hd=32.
//  k0: x,W -> bf16 once (ws).
//  k1 (per (b,h) block, 704 thr = 11 waves):
//   p1: wave w = m-tile w. Q computed TRANSPOSED (A/B swap) -> stays in regs.
//       K -> KS LDS, V^T -> VT LDS. W B-frags from padded LDS.
//   p2: S^T = K·Q^T and O^T = V^T·P^T, both via 16x16x32 MFMA with a shared
//       k-slot permutation (slot(q,j) = j<4 ? q*4+j : 16+q*4+j-4), so Q and P
//       never touch LDS. Mask, exp2-softmax (unnormalized P, 1/sum folded
//       into epilogue), float4 stores.
//  R7: replaced unavailable 16x16x16 builtin (host-pass #error) with
//      permuted-K 16x16x32; all fragment orientations re-derived from R5's
//      verified K/VT layouts.
//  R8: XCD co-location swizzle — all 8 heads of a batch b map to the same
//      XCD so their shared X16 rows hit the per-XCD L2. Bijective remap.
//  R9: LDS bank-conflict fix — KS row stride 40->44 ushorts (80B==20 banks,
//      period-8 c/c+8 same-bank -> 88B==22 banks, full 16-way spread) and
//      VT 200->204 (400B==4 banks -> 408B==6 banks). Phase-2 ds_read_b64
//      conflicts drop ~8-way -> ~4-way floor. Alignment preserved (8B).
// ---------------------------------------------------------------------------

#define SEQ    176
#define HD     32
#define DIN    128
#define DMODEL 256

#define KSTRIDE 44   // KS row stride in ushorts (was 40)
#define VSTRIDE 204  // VT row stride in ushorts (was 200)

typedef unsigned short ushort_t;
typedef __attribute__((ext_vector_type(8))) short short8;
typedef __attribute__((ext_vector_type(4))) short short4v;
typedef __attribute__((ext_vector_type(4))) float float4v;
typedef __attribute__((ext_vector_type(4))) unsigned short ushort4v;

// ws layout (bytes): WT bf16 [3][8][32][128] @ 0; X16 bf16 [256*176*128] @ 196608
#define WS_WT 0u
#define WS_X  196608u

// LDS (ushort units), total 27328 ush = 54656 B
//  WS @ 0      [3][32][136]    = 13056  (phase 1 W slices, padded)
//  KS @ 13056  [176][KSTRIDE]  = 7744   (K, row-major seq x feat)
//  VT @ 20800  [32][VSTRIDE]   = 6528   (V^T, feat x seq; cols 176..191 zeroed)
#define OFF_KS 13056
#define OFF_VT (OFF_KS + 176 * KSTRIDE)
#define SMEM_TOTAL (OFF_VT + 32 * VSTRIDE)

__device__ __forceinline__ ushort_t f2bf(float f) {
    union { float f; unsigned int u; } cv; cv.f = f;
    unsigned int u = cv.u;
    unsigned int rb = 0x7FFFu + ((u >> 16) & 1u);   // RTNE
    return (ushort_t)((u + rb) >> 16);
}

// ---------------- k0: one-shot bf16 conversion ----------------------------
__global__ __launch_bounds__(256)
void k0_conv(const float* __restrict__ x,
             const float* __restrict__ Wq, const float* __restrict__ Wk,
             const float* __restrict__ Wv,
             ushort_t* __restrict__ WT, ushort_t* __restrict__ X16)
{
    int bid = blockIdx.x;
    if (bid < 5632) {
        int f4 = bid * 256 + threadIdx.x;
        float4 v = reinterpret_cast<const float4*>(x)[f4];
        ushort4v o;
        o.x = f2bf(v.x); o.y = f2bf(v.y); o.z = f2bf(v.z); o.w = f2bf(v.w);
        reinterpret_cast<ushort4v*>(X16)[f4] = o;
    } else {
        int idx = (bid - 5632) * 256 + threadIdx.x;   // < 24576
        int e = idx * 4;
        int mat = e >> 15, h = (e >> 12) & 7, n = (e >> 7) & 31, k = e & 127;
        const float* W = (mat == 0) ? Wq : ((mat == 1) ? Wk : Wv);
        ushort4v o;
        o.x = f2bf(W[(k + 0) * DMODEL + h * HD + n]);
        o.y = f2bf(W[(k + 1) * DMODEL + h * HD + n]);
        o.z = f2bf(W[(k + 2) * DMODEL + h * HD + n]);
        o.w = f2bf(W[(k + 3) * DMODEL + h * HD + n]);
        reinterpret_cast<ushort4v*>(WT)[idx] = o;
    }
}

// ---------------- k1: fused attention -------------------------------------
__global__ __launch_bounds__(704, 6)
void k1_attn(const ushort_t* __restrict__ X16, const ushort_t* __restrict__ WT,
             const float* __restrict__ bq, const float* __restrict__ bk,
             const float* __restrict__ bv, float* __restrict__ out)
{
    __shared__ ushort_t smem[SMEM_TOTAL];
    ushort_t* WS = smem;                 // [3][32][136]
    ushort_t* KS = smem + OFF_KS;        // [176][KSTRIDE]
    ushort_t* VT = smem + OFF_VT;        // [32][VSTRIDE]

    const int tid  = threadIdx.x;
    const int lane = tid & 63;
    const int w    = tid >> 6;           // wave 0..10 = m-tile / row-tile
    const int c    = lane & 15;
    const int q    = lane >> 4;

    // R8: XCD co-location. Dispatch sends blockIdx i to XCD i%8; group all
    // 8 heads of a batch onto one XCD so X16 rows are L2-shared.
    const int xcd = blockIdx.x & 7;      // physical XCD (heuristic)
    const int j   = blockIdx.x >> 3;     // 0..255 within XCD
    const int b   = xcd * 32 + (j >> 3); // 32 batches per XCD
    const int h   = j & 7;               // 8 heads of b, same XCD, adjacent

    // ---- stage W-slice (head h): 1536 chunks of 16 B, 16 chunks per n-row
#pragma unroll
    for (int it = 0; it < 3; ++it) {
        int c8 = tid + it * 704;
        if (c8 < 1536) {
            int mat = c8 >> 9, rem = c8 & 511, n = rem >> 4, kc = rem & 15;
            short8 v = *reinterpret_cast<const short8*>(
                WT + (size_t)(((mat * 8 + h) * 32 + n) * 128 + kc * 8));
            *reinterpret_cast<short8*>(WS + (mat * 32 + n) * 136 + kc * 8) = v;
        }
    }
    // zero VT pad cols [176,192) (rows 0..31, 16 cols = 512 threads)
    if (tid < 512) {
        VT[(tid >> 4) * VSTRIDE + 176 + (tid & 15)] = 0;
    }
    __syncthreads();   // barrier 0: W staging is cross-wave

    // ---- phase 1: QKV for m-tile w; x fragments direct from global bf16
    const ushort_t* xr = X16 + ((size_t)b * SEQ + w * 16 + c) * DIN;
    short8 xf[4];
#pragma unroll
    for (int kk = 0; kk < 4; ++kk)
        xf[kk] = *reinterpret_cast<const short8*>(xr + kk * 32 + q * 8);

    const float qscale = 0.17677669529663687f * 1.4426950408889634f; // 1/sqrt(32)*log2e

    // Q transposed (A=W, B=x): lane(c,q) gets Q[t=w*16+c][f=nt*16+q*4+r].
    // Packed as one short8 in permuted k-slot order: j<4 -> d=q*4+j,
    // j>=4 -> d=16+q*4+(j-4).
    short8 qf8;
#pragma unroll
    for (int nt = 0; nt < 2; ++nt) {
        const ushort_t* wrow = WS + (nt * 16 + c) * 136 + q * 8;
        float4v acc = {0.f, 0.f, 0.f, 0.f};
#pragma unroll
        for (int kk = 0; kk < 4; ++kk) {
            short8 wf = *reinterpret_cast<const short8*>(wrow + kk * 32);
            acc = __builtin_amdgcn_mfma_f32_16x16x32_bf16(wf, xf[kk], acc, 0, 0, 0);
        }
        float4 bb = *reinterpret_cast<const float4*>(bq + h * HD + nt * 16 + q * 4);
        qf8[nt * 4 + 0] = (short)f2bf((acc[0] + bb.x) * qscale);
        qf8[nt * 4 + 1] = (short)f2bf((acc[1] + bb.y) * qscale);
        qf8[nt * 4 + 2] = (short)f2bf((acc[2] + bb.z) * qscale);
        qf8[nt * 4 + 3] = (short)f2bf((acc[3] + bb.w) * qscale);
    }
    // K normal (A=x, B=W): C = K[t=w*16+q*4+r][d=nt*16+c] -> KS[t][d]
#pragma unroll
    for (int nt = 0; nt < 2; ++nt) {
        const ushort_t* wrow = WS + (32 + nt * 16 + c) * 136 + q * 8;
        float4v acc = {0.f, 0.f, 0.f, 0.f};
#pragma unroll
        for (int kk = 0; kk < 4; ++kk) {
            short8 wf = *reinterpret_cast<const short8*>(wrow + kk * 32);
            acc = __builtin_amdgcn_mfma_f32_16x16x32_bf16(xf[kk], wf, acc, 0, 0, 0);
        }
        float bia = bk[h * HD + nt * 16 + c];
#pragma unroll
        for (int r = 0; r < 4; ++r)
            KS[(w * 16 + q * 4 + r) * KSTRIDE + nt * 16 + c] = f2bf(acc[r] + bia);
    }
    // V transposed (A=W, B=x) + ReLU: lane(c,q) -> VT[d=nt*16+q*4+r][t=w*16+c]
#pragma unroll
    for (int nt = 0; nt < 2; ++nt) {
        const ushort_t* wrow = WS + (64 + nt * 16 + c) * 136 + q * 8;
        float4v acc = {0.f, 0.f, 0.f, 0.f};
#pragma unroll
        for (int kk = 0; kk < 4; ++kk) {
            short8 wf = *reinterpret_cast<const short8*>(wrow + kk * 32);
            acc = __builtin_amdgcn_mfma_f32_16x16x32_bf16(wf, xf[kk], acc, 0, 0, 0);
        }
        float4 bb = *reinterpret_cast<const float4*>(bv + h * HD + nt * 16 + q * 4);
#pragma unroll
        for (int r = 0; r < 4; ++r) {
            float bias_r = (r == 0) ? bb.x : (r == 1) ? bb.y : (r == 2) ? bb.z : bb.w;
            float v = acc[r] + bias_r;
            v = v > 0.f ? v : 0.f;
            VT[(nt * 16 + q * 4 + r) * VSTRIDE + w * 16 + c] = f2bf(v);
        }
    }
    __syncthreads();   // barrier 1: KS/VT complete

    // ---- phase 2: attention; lane(c,q) owns score column t = w*16+c ----
    const int t_row = w * 16 + c;
    const int lo = (t_row / 22) * 22;    // start of t's 22-joint time block
    float su = 0.f;
    short8 pf[6];                        // P^T fragments, paired n-tiles
    pf[5] = (short8){0, 0, 0, 0, 0, 0, 0, 0};   // n=11 pad half stays zero
#pragma unroll
    for (int n = 0; n < 11; ++n) {
        // A = K row t' = n*16+c, gathered in permuted k-slot order
        const ushort_t* krow = KS + (n * 16 + c) * KSTRIDE;
        short4v ka = *reinterpret_cast<const short4v*>(krow + q * 4);
        short4v kb = *reinterpret_cast<const short4v*>(krow + 16 + q * 4);
        short8 kf = {ka.x, ka.y, ka.z, ka.w, kb.x, kb.y, kb.z, kb.w};
        float4v s = {0.f, 0.f, 0.f, 0.f};
        s = __builtin_amdgcn_mfma_f32_16x16x32_bf16(kf, qf8, s, 0, 0, 0);
        // S^T[t' = n*16+q*4+r][t = t_row]; mask same-block off-diagonal
#pragma unroll
        for (int r = 0; r < 4; ++r) {
            int tp = n * 16 + q * 4 + r;
            float sv = (((unsigned)(tp - lo) < 22u) && (tp != t_row)) ? -1e30f : s[r];
            float e = __builtin_amdgcn_exp2f(sv);
            su += e;
            pf[n >> 1][(n & 1) * 4 + r] = (short)f2bf(e);
        }
    }
    su += __shfl_xor(su, 16, 64);        // reduce across the 4 quads
    su += __shfl_xor(su, 32, 64);
    const float invs = 1.0f / su;

    // PV: O^T[d][t] = sum_t' V^T[d][t'] P^T[t'][t]; A = V^T pair-gathered
    float* ob = out + ((size_t)b * SEQ + t_row) * DMODEL + h * HD;
#pragma unroll
    for (int mt = 0; mt < 2; ++mt) {
        const ushort_t* vrow = VT + (mt * 16 + c) * VSTRIDE;
        float4v o = {0.f, 0.f, 0.f, 0.f};
#pragma unroll
        for (int g = 0; g < 6; ++g) {
            short4v va = *reinterpret_cast<const short4v*>(vrow + (2 * g) * 16 + q * 4);
            short4v vb = *reinterpret_cast<const short4v*>(vrow + (2 * g + 1) * 16 + q * 4);
            short8 vf = {va.x, va.y, va.z, va.w, vb.x, vb.y, vb.z, vb.w};
            o = __builtin_amdgcn_mfma_f32_16x16x32_bf16(vf, pf[g], o, 0, 0, 0);
        }
        float4 st;
        st.x = o[0] * invs; st.y = o[1] * invs;
        st.z = o[2] * invs; st.w = o[3] * invs;
        *reinterpret_cast<float4*>(ob + mt * 16 + q * 4) = st;
    }
}

extern "C" void kernel_launch(void* const* d_in, const int* in_sizes, int n_in,
                              void* d_out, int out_size, void* d_ws, size_t ws_size,
                              hipStream_t stream) {
    const float* x  = (const float*)d_in[0];
    const float* Wq = (const float*)d_in[1];
    const float* bq = (const float*)d_in[2];
    const float* Wk = (const float*)d_in[3];
    const float* bk = (const float*)d_in[4];
    const float* Wv = (const float*)d_in[5];
    const float* bv = (const float*)d_in[6];
    float* out = (float*)d_out;

    char* ws = (char*)d_ws;
    ushort_t* WT  = (ushort_t*)(ws + WS_WT);
    ushort_t* X16 = (ushort_t*)(ws + WS_X);

    k0_conv<<<dim3(5728), dim3(256), 0, stream>>>(x, Wq, Wk, Wv, WT, X16);
    k1_attn<<<dim3(2048), dim3(704), 0, stream>>>(X16, WT, bq, bk, bv, out);
}